// Round 6
// baseline (184.012 us; speedup 1.0000x reference)
//
#include <hip/hip_runtime.h>
#include <hip/hip_bf16.h>

// Problem constants
constexpr int B  = 2;
constexpr int S  = 2048;
constexpr int E  = 1024;
constexpr int H  = 16;
constexpr int DK = 64;
constexpr int M  = B * S;            // 4096 rows of x
constexpr int N3 = 3 * E;            // stacked [Wk; Wv; Wq]
constexpr long RSZ = (long)B * H * S * DK;  // one output region (4.19M elems)

// Q scale: 1/sqrt(DK) * log2(e) -> softmax via raw v_exp_f32 (base-2), no mul.
#define QSCALE 0.18033688011112042f

using bf16x8 = __attribute__((ext_vector_type(8))) __bf16;
using bf16x4 = __attribute__((ext_vector_type(4))) __bf16;
using f32x4  = __attribute__((ext_vector_type(4))) float;

// async global->LDS, 16B/lane; LDS base wave-uniform, lane i lands at +i*16 B.
__device__ __forceinline__ void async16(__bf16* lds, const __bf16* g) {
    __builtin_amdgcn_global_load_lds(
        (const __attribute__((address_space(1))) void*)g,
        (__attribute__((address_space(3))) void*)lds, 16, 0, 0);
}

// ---------------- fused QKV GEMM v4: cvt fused into staging ----------------
// R5 audit: total-minus-attn is a constant ~117us across all rounds, far above
// the ~45us roofline for cvt+qkv. kernel_launch's fast path needs ws >= 39.8MB
// (kvq 25.2 + xb/wall 14.6); if the harness gives less, the slow proj fallback
// (3 unstaged fp32 GEMMs ~= 117us) runs silently. attn itself proves ws >=
// 25.2MB. v4 removes the xb/wall dependency: stage x/W fp32 directly from
// global into regs, cvt to bf16, ds_write into the SAME LDS layout (swizzle
// key (row>>1)&3 reproduced on the write side; frag reads/MFMA/epilogues
// unchanged). dbuf 32KB LDS; loads issued one iter ahead (T14), lgkm-only
// barrier keeps the global-load pipeline alive across iters.
__global__ __launch_bounds__(256, 3)
void qkv_fused(const float* __restrict__ x, const float* __restrict__ Wk,
               const float* __restrict__ Wv, const float* __restrict__ Wq,
               const float* __restrict__ theta, __bf16* __restrict__ kvq) {
    __shared__ __align__(1024) __bf16 smem[4 * 4096];   // A0|A1|B0|B1 = 32 KB
    __bf16* tile = smem;                                // epilogue alias: 128x128 = 32 KB

    const int t    = threadIdx.x;
    const int lane = t & 63;
    const int w    = t >> 6;
    const int quad = lane >> 4;
    const int l16  = lane & 15;
    const int wm   = w >> 1, wn = w & 1;      // 2x2 wave grid, 64x64 each
    const int mbase = blockIdx.y * 128;
    const int nbase = blockIdx.x * 128;

    f32x4 acc[4][4];
    #pragma unroll
    for (int i = 0; i < 4; i++)
        #pragma unroll
        for (int j = 0; j < 4; j++)
            acc[i][j] = f32x4{0.f, 0.f, 0.f, 0.f};

    // staging: thread owns row sr = t>>1, phys chunks {cg, cg+1} (8 bf16 each).
    // phys chunk p holds logical chunk p ^ key, key = (sr>>1)&3 -- identical to
    // the old DMA pre-swizzle (srcc = (lane&3)^((lane>>3)&3)); frag reads use
    // phys = quad ^ ((l16>>1)&3) and (sr>>1)&3 == (l16>>1)&3 for sr==l16 mod 16.
    const int sr  = t >> 1;                   // 0..127
    const int cg  = (t & 1) * 2;
    const int key = (sr >> 1) & 3;
    const float* asrc = x + (long)(mbase + sr) * E;
    const int brow = nbase + sr;              // 0..3071 in stacked [Wk;Wv;Wq]
    const float* wsel = (brow >> 10) == 0 ? Wk : (brow >> 10) == 1 ? Wv : Wq;
    const float* bsrc = wsel + (long)(brow & 1023) * E;

    float4 ra[2][2], rb[2][2];                // [chunk][half], step in flight
    auto load_step = [&](int kk) {
        #pragma unroll
        for (int c = 0; c < 2; c++) {
            const int lc = (cg + c) ^ key;
            ra[c][0] = *reinterpret_cast<const float4*>(asrc + kk + lc * 8);
            ra[c][1] = *reinterpret_cast<const float4*>(asrc + kk + lc * 8 + 4);
            rb[c][0] = *reinterpret_cast<const float4*>(bsrc + kk + lc * 8);
            rb[c][1] = *reinterpret_cast<const float4*>(bsrc + kk + lc * 8 + 4);
        }
    };
    auto write_buf = [&](int buf) {
        #pragma unroll
        for (int c = 0; c < 2; c++) {
            bf16x8 va, vb;
            va[0] = (__bf16)ra[c][0].x; va[1] = (__bf16)ra[c][0].y;
            va[2] = (__bf16)ra[c][0].z; va[3] = (__bf16)ra[c][0].w;
            va[4] = (__bf16)ra[c][1].x; va[5] = (__bf16)ra[c][1].y;
            va[6] = (__bf16)ra[c][1].z; va[7] = (__bf16)ra[c][1].w;
            vb[0] = (__bf16)rb[c][0].x; vb[1] = (__bf16)rb[c][0].y;
            vb[2] = (__bf16)rb[c][0].z; vb[3] = (__bf16)rb[c][0].w;
            vb[4] = (__bf16)rb[c][1].x; vb[5] = (__bf16)rb[c][1].y;
            vb[6] = (__bf16)rb[c][1].z; vb[7] = (__bf16)rb[c][1].w;
            *reinterpret_cast<bf16x8*>(&smem[buf * 4096 + sr * 32 + (cg + c) * 8]) = va;
            *reinterpret_cast<bf16x8*>(&smem[8192 + buf * 4096 + sr * 32 + (cg + c) * 8]) = vb;
        }
    };

    // prologue: step 0 staged to buf0; step 1 in regs
    load_step(0);
    write_buf(0);
    load_step(32);
    asm volatile("s_waitcnt lgkmcnt(0)" ::: "memory");
    asm volatile("s_barrier" ::: "memory");

    constexpr int ITERS = E / 32;   // 32
    for (int it = 0; it < ITERS; it++) {
        const int cur = it & 1;
        const __bf16* Asb = smem + cur * 4096;
        const __bf16* Bsb = smem + 8192 + cur * 4096;
        const int csw = (l16 >> 1) & 3;
        bf16x8 a[4], b[4];
        #pragma unroll
        for (int i = 0; i < 4; i++)
            a[i] = *reinterpret_cast<const bf16x8*>(
                &Asb[(wm * 64 + i * 16 + l16) * 32 + (quad ^ csw) * 8]);
        #pragma unroll
        for (int j = 0; j < 4; j++)
            b[j] = *reinterpret_cast<const bf16x8*>(
                &Bsb[(wn * 64 + j * 16 + l16) * 32 + (quad ^ csw) * 8]);
        #pragma unroll
        for (int i = 0; i < 4; i++)
            #pragma unroll
            for (int j = 0; j < 4; j++)
                acc[i][j] = __builtin_amdgcn_mfma_f32_16x16x32_bf16(a[i], b[j], acc[i][j], 0, 0, 0);

        if (it + 1 < ITERS) write_buf(cur ^ 1);      // regs hold step it+1
        if (it + 2 < ITERS) load_step((it + 2) * 32);
        if (it + 1 < ITERS) {
            asm volatile("s_waitcnt lgkmcnt(0)" ::: "memory");  // writes visible
            asm volatile("s_barrier" ::: "memory");             // vmem stays in flight
        }
    }

    const int region = nbase >> 10;           // block-uniform 0=K 1=V 2=Q
    const int bb = mbase >> 11;
    if (region == 1) {
        __syncthreads();                      // full drain before aliasing smem
        #pragma unroll
        for (int i = 0; i < 4; i++) {
            const int cchunk = wm * 8 + i * 2 + (quad >> 1);
            #pragma unroll
            for (int j = 0; j < 4; j++) {
                const int cirb = wn * 64 + j * 16 + l16;
                const int cs = cchunk ^ l16;
                bf16x4 pk;
                #pragma unroll
                for (int r = 0; r < 4; r++) pk[r] = (__bf16)acc[i][j][r];
                *reinterpret_cast<bf16x4*>(&tile[cirb * 128 + cs * 8 + (quad & 1) * 4]) = pk;
            }
        }
        __syncthreads();
        const int h0 = (nbase & 1023) >> 6;
        __bf16* vt = kvq + RSZ;               // V^T region: [B,H,DK,S]
        #pragma unroll
        for (int p = 0; p < 8; p++) {
            const int dcol = p * 16 + (t >> 4);
            const int lc = t & 15;
            const int cs2 = lc ^ (dcol & 15);
            bf16x8 vv = *reinterpret_cast<const bf16x8*>(&tile[dcol * 128 + cs2 * 8]);
            const int hh = h0 + (dcol >> 6), d = dcol & 63;
            *reinterpret_cast<bf16x8*>(
                &vt[((long)(bb * H + hh) * DK + d) * S + (mbase & 2047) + lc * 8]) = vv;
        }
    } else {
        __bf16* dst = kvq + (region == 2 ? 2 * RSZ : 0);
        float th[4];
        if (region == 2) {
            #pragma unroll
            for (int j = 0; j < 4; j++) th[j] = theta[j * 16 + l16];
        }
        #pragma unroll
        for (int i = 0; i < 4; i++) {
            const int row0 = mbase + wm * 64 + i * 16 + quad * 4;
            #pragma unroll
            for (int j = 0; j < 4; j++) {
                const int cir = (nbase & 1023) + wn * 64 + j * 16 + l16;
                const int h = cir >> 6, d = cir & 63;
                #pragma unroll
                for (int r = 0; r < 4; r++) {
                    const int s = (row0 + r) & 2047;
                    float v = acc[i][j][r];
                    if (region == 2) v = cosf(v + th[j]) * QSCALE;  // fold 1/sqrt(DK)*log2e
                    dst[((long)(bb * H + h) * S + s) * DK + d] = (__bf16)v;
                }
            }
        }
    }
}

// ---------------- attention v10 (verified 53.2us): S^T + KT=64 + distance-2 ----------------
// Best measured attn across v10-v14 experiments (v11 ILP: neutral; v12
// reg-direct K/V: 2.4x worse; v13 small-tile occupancy: 1.37x worse; v14
// in-reg P via 32x32: 1.06x worse). Reverted verbatim.
__global__ __launch_bounds__(256, 2)
void attn_kernel(const __bf16* __restrict__ q_ws, const __bf16* __restrict__ k_ws,
                 const __bf16* __restrict__ v_ws, float* __restrict__ out) {
    __shared__ __align__(1024) __bf16 Ks[3][64 * 64];   // [key][d] swizzled, 8 KB each
    __shared__ __align__(1024) __bf16 Vs[3][64 * 64];   // [d][key] swizzled, 8 KB each
    __shared__ __align__(16)   __bf16 Pl[4][32 * 72];   // per-wave P [qrow][key], stride 72
    __shared__ __align__(16)   float  ls_lds[4][32];

    const int lane = threadIdx.x & 63;
    const int w    = threadIdx.x >> 6;          // 0..3
    const int quad = lane >> 4;
    const int l16  = lane & 15;

    // XCD swizzle: 4 bh per id%8 class -> per-XCD K/V set 2MB < 4MB L2 (R6-verified)
    const int id    = blockIdx.x;
    const int bh    = (id & 7) + 8 * ((id >> 3) & 3);
    const int qbase = (id >> 5) * 128 + w * 32;  // wave owns 32 q-rows

    const __bf16* qp = q_ws + (long)bh * S * DK;
    const __bf16* kp = k_ws + (long)bh * S * DK;
    const __bf16* vp = v_ws + (long)bh * DK * S;   // [DK][S]

    // staging: 8 rows x 8 chunks(16B) per async16; source chunk XOR-swizzled
    const int sr  = lane >> 3;
    const int scs = (lane & 7) ^ sr;

    // Q B-frags resident: B[k=d=ks*32+quad*8+j][n=qrow=nt*16+l16]
    bf16x8 bq[2][2];
    #pragma unroll
    for (int nt = 0; nt < 2; nt++)
        #pragma unroll
        for (int ks = 0; ks < 2; ks++)
            bq[nt][ks] = *reinterpret_cast<const bf16x8*>(
                qp + (long)(qbase + nt * 16 + l16) * DK + ks * 32 + quad * 8);

    f32x4 o[2][4];     // O[qrow-tile mt][d-tile nt]
    #pragma unroll
    for (int i = 0; i < 2; i++)
        #pragma unroll
        for (int j = 0; j < 4; j++) o[i][j] = f32x4{0.f, 0.f, 0.f, 0.f};
    float lsum[2] = {0.f, 0.f};   // per-lane partial row sums, qrow = nt*16+l16

    // prologue: tiles 0,1 into buffers 0,1 — 4 DMA issues per tile per wave
    #pragma unroll
    for (int pt = 0; pt < 2; pt++) {
        #pragma unroll
        for (int i = 0; i < 2; i++) {
            const int row = w * 16 + i * 8;
            async16(&Ks[pt][row * 64], kp + (long)(pt * 64 + row + sr) * DK + scs * 8);
            async16(&Vs[pt][row * 64], vp + (long)(row + sr) * S + pt * 64 + scs * 8);
        }
    }

    int cur = 0;
    constexpr int ITERS = S / 64;   // 32
    for (int it = 0; it < ITERS; it++) {
        if (it < ITERS - 1) asm volatile("s_waitcnt vmcnt(4)" ::: "memory");
        else                asm volatile("s_waitcnt vmcnt(0)" ::: "memory");
        asm volatile("s_barrier" ::: "memory");   // raw: no drain

        if (it + 2 < ITERS) {
            const int kt2 = (it + 2) * 64;
            const int pb  = (cur == 0) ? 2 : cur - 1;
            #pragma unroll
            for (int i = 0; i < 2; i++) {
                const int row = w * 16 + i * 8;
                async16(&Ks[pb][row * 64], kp + (long)(kt2 + row + sr) * DK + scs * 8);
                async16(&Vs[pb][row * 64], vp + (long)(row + sr) * S + kt2 + scs * 8);
            }
        }

        // ---- S^T = K Q^T : C[key(regs) 64][qrow(lanes) 32] ----
        f32x4 sacc[4][2];  // [key-tile mt][qrow-tile nt]
        #pragma unroll
        for (int i = 0; i < 4; i++)
            #pragma unroll
            for (int j = 0; j < 2; j++) sacc[i][j] = f32x4{0.f, 0.f, 0.f, 0.f};
        #pragma unroll
        for (int ks = 0; ks < 2; ks++) {
            bf16x8 ak[4];
            #pragma unroll
            for (int mt = 0; mt < 4; mt++)
                ak[mt] = *reinterpret_cast<const bf16x8*>(
                    &Ks[cur][(mt * 16 + l16) * 64 + ((ks * 4 + quad) ^ (l16 & 7)) * 8]);
            #pragma unroll
            for (int mt = 0; mt < 4; mt++)
                #pragma unroll
                for (int nt = 0; nt < 2; nt++)
                    sacc[mt][nt] = __builtin_amdgcn_mfma_f32_16x16x32_bf16(
                        ak[mt], bq[nt][ks], sacc[mt][nt], 0, 0, 0);
        }

        // ---- P = exp2(S^T): 4 consecutive keys (regs) -> one b64 store ----
        #pragma unroll
        for (int mt = 0; mt < 4; mt++)
            #pragma unroll
            for (int nt = 0; nt < 2; nt++) {
                float p0 = __builtin_amdgcn_exp2f(sacc[mt][nt][0]);
                float p1 = __builtin_amdgcn_exp2f(sacc[mt][nt][1]);
                float p2 = __builtin_amdgcn_exp2f(sacc[mt][nt][2]);
                float p3 = __builtin_amdgcn_exp2f(sacc[mt][nt][3]);
                lsum[nt] += (p0 + p1) + (p2 + p3);
                bf16x4 pk;
                pk[0] = (__bf16)p0; pk[1] = (__bf16)p1;
                pk[2] = (__bf16)p2; pk[3] = (__bf16)p3;
                *reinterpret_cast<bf16x4*>(
                    &Pl[w][(nt * 16 + l16) * 72 + mt * 16 + quad * 4]) = pk;
            }

        // ---- O += P V : A=P[m=qrow][k=key], B=V[k=key][n=d], 2 k-halves ----
        #pragma unroll
        for (int kh = 0; kh < 2; kh++) {
            bf16x8 bv[4];
            #pragma unroll
            for (int nt = 0; nt < 4; nt++)
                bv[nt] = *reinterpret_cast<const bf16x8*>(
                    &Vs[cur][(nt * 16 + l16) * 64 + ((kh * 4 + quad) ^ (l16 & 7)) * 8]);
            #pragma unroll
            for (int mt = 0; mt < 2; mt++) {
                bf16x8 ap = *reinterpret_cast<const bf16x8*>(
                    &Pl[w][(mt * 16 + l16) * 72 + kh * 32 + quad * 8]);
                #pragma unroll
                for (int nt = 0; nt < 4; nt++)
                    o[mt][nt] = __builtin_amdgcn_mfma_f32_16x16x32_bf16(
                        ap, bv[nt], o[mt][nt], 0, 0, 0);
            }
        }

        cur = (cur == 2) ? 0 : cur + 1;
    }

    // ---- finalize l: reduce partials across the 4 quads, broadcast via LDS ----
    #pragma unroll
    for (int nt = 0; nt < 2; nt++) {
        float v = lsum[nt];
        v += __shfl_xor(v, 16);
        v += __shfl_xor(v, 32);
        ls_lds[w][nt * 16 + l16] = v;   // quads duplicate-write same value (benign)
    }

    // ---- epilogue: out[b][s][h*64+d] = O / l ----
    const int b = bh >> 4, h = bh & 15;
    #pragma unroll
    for (int mt = 0; mt < 2; mt++) {
        f32x4 lv = *reinterpret_cast<const f32x4*>(&ls_lds[w][mt * 16 + quad * 4]);
        #pragma unroll
        for (int r = 0; r < 4; r++) {
            const float inv = 1.0f / lv[r];
            const int srow = qbase + mt * 16 + quad * 4 + r;
            #pragma unroll
            for (int nt = 0; nt < 4; nt++)
                out[(long)(b * S + srow) * E + h * DK + nt * 16 + l16] = o[mt][nt][r] * inv;
        }
    }
}

extern "C" void kernel_launch(void* const* d_in, const int* in_sizes, int n_in,
                              void* d_out, int out_size, void* d_ws, size_t ws_size,
                              hipStream_t stream) {
    const float* x     = (const float*)d_in[0];
    const float* Wk    = (const float*)d_in[1];
    const float* Wv    = (const float*)d_in[2];
    const float* Wq    = (const float*)d_in[3];
    const float* theta = (const float*)d_in[4];
    float* out = (float*)d_out;

    // ws: kvq[3*RSZ: K | V^T | Q] -- 25.2 MB, the minimum attn itself requires
    __bf16* kvq  = (__bf16*)d_ws;
    __bf16* k_ws = kvq;
    __bf16* v_t  = kvq + RSZ;
    __bf16* q_ws = kvq + 2 * RSZ;

    dim3 blk(256);
    qkv_fused<<<dim3(N3 / 128, M / 128), blk, 0, stream>>>(x, Wk, Wv, Wq, theta, kvq);
    attn_kernel<<<dim3(512), blk, 0, stream>>>(q_ws, k_ws, v_t, out);
}

// Round 8
// 173.628 us; speedup vs baseline: 1.0598x; 1.0598x over previous
//
#include <hip/hip_runtime.h>
#include <hip/hip_bf16.h>

// Problem constants
constexpr int B  = 2;
constexpr int S  = 2048;
constexpr int E  = 1024;
constexpr int H  = 16;
constexpr int DK = 64;
constexpr int M  = B * S;            // 4096 rows of x
constexpr int N3 = 3 * E;            // stacked [Wk; Wv; Wq]
constexpr long RSZ = (long)B * H * S * DK;  // one output region (4.19M elems)

// Q scale: 1/sqrt(DK) * log2(e) -> softmax via raw v_exp_f32 (base-2), no mul.
#define QSCALE 0.18033688011112042f

using bf16x8 = __attribute__((ext_vector_type(8))) __bf16;
using bf16x4 = __attribute__((ext_vector_type(4))) __bf16;
using f32x4  = __attribute__((ext_vector_type(4))) float;

// async global->LDS, 16B/lane; LDS base wave-uniform, lane i lands at +i*16 B.
__device__ __forceinline__ void async16(__bf16* lds, const __bf16* g) {
    __builtin_amdgcn_global_load_lds(
        (const __attribute__((address_space(1))) void*)g,
        (__attribute__((address_space(3))) void*)lds, 16, 0, 0);
}

// ---------------- cvt: x and stacked W's -> bf16 (into d_out scratch) ----------------
// R6 post-mortem: ws_size < 39.8MB (proven by R0-R5's constant ~117us proj
// fallback + R6's fused-kernel accounting), so xb/wall now live in d_out
// (16.8 MB, written only by attn at the very end): xb 8.4 + wall 6.3 = 14.7 MB.
__global__ __launch_bounds__(256)
void cvt_kernel(const float* __restrict__ x, const float* __restrict__ Wk,
                const float* __restrict__ Wv, const float* __restrict__ Wq,
                __bf16* __restrict__ xb, __bf16* __restrict__ wall) {
    const long e = ((long)blockIdx.x * 256 + threadIdx.x) * 4;
    const float* src;
    __bf16* dst;
    if (e < (long)M * E) { src = x + e; dst = xb + e; }
    else {
        const long e2 = e - (long)M * E;
        const int which = (int)(e2 >> 20);
        const long off  = e2 & ((1L << 20) - 1);
        src = (which == 0 ? Wk : which == 1 ? Wv : Wq) + off;
        dst = wall + e2;
    }
    float4 f = *reinterpret_cast<const float4*>(src);
    bf16x4 o;
    o[0] = (__bf16)f.x; o[1] = (__bf16)f.y; o[2] = (__bf16)f.z; o[3] = (__bf16)f.w;
    *reinterpret_cast<bf16x4*>(dst) = o;
}

// ---------------- QKV GEMM v5: DMA-staged core + proj-proven epilogues ----------------
// Core: m97-lineage 128x128 tile, global_load_lds width=16, triple-buffer,
// distance-2 counted vmcnt (never 0 in steady state), raw s_barrier.
// Epilogues: direct stores using the index formulas the proj fallback has
// been passing with for 6 rounds (V^T gets bf16x4 over 4 consecutive s).
__global__ __launch_bounds__(256, 3)
void qkv_gemm(const __bf16* __restrict__ xb, const __bf16* __restrict__ wall,
              const float* __restrict__ theta, __bf16* __restrict__ kvq) {
    __shared__ __align__(1024) __bf16 smem[6 * 128 * 32];   // A0|A1|A2|B0|B1|B2 = 48 KB

    const int t    = threadIdx.x;
    const int lane = t & 63;
    const int w    = t >> 6;
    const int quad = lane >> 4;
    const int l16  = lane & 15;
    const int wm   = w >> 1, wn = w & 1;      // 2x2 wave grid, 64x64 each
    const int mbase = blockIdx.y * 128;
    const int nbase = blockIdx.x * 128;

    f32x4 acc[4][4];
    #pragma unroll
    for (int i = 0; i < 4; i++)
        #pragma unroll
        for (int j = 0; j < 4; j++)
            acc[i][j] = f32x4{0.f, 0.f, 0.f, 0.f};

    const int srow = lane >> 2;
    const int srcc = (lane & 3) ^ ((lane >> 3) & 3);
    const __bf16* ga = xb   + (long)(mbase + srow) * E + srcc * 8;
    const __bf16* gb = wall + (long)(nbase + srow) * E + srcc * 8;

    const int csw = (l16 >> 1) & 3;

    // prologue: tiles 0 and 1 into buffers 0 and 1 (8 loads outstanding)
    #pragma unroll
    for (int pt = 0; pt < 2; pt++) {
        #pragma unroll
        for (int c = 0; c < 2; c++) {
            async16(smem + pt * 4096 +         (c * 64 + w * 16) * 32,
                    ga + (long)(c * 64 + w * 16) * E + pt * 32);
            async16(smem + pt * 4096 + 12288 + (c * 64 + w * 16) * 32,
                    gb + (long)(c * 64 + w * 16) * E + pt * 32);
        }
    }

    int cur = 0;
    constexpr int ITERS = E / 32;   // 32
    for (int it = 0; it < ITERS; it++) {
        if (it < ITERS - 1) asm volatile("s_waitcnt vmcnt(4)" ::: "memory");
        else                asm volatile("s_waitcnt vmcnt(0)" ::: "memory");
        asm volatile("s_barrier" ::: "memory");   // raw: no drain

        if (it + 2 < ITERS) {
            const int pb  = (cur == 0) ? 2 : cur - 1;
            const int kk2 = (it + 2) * 32;
            #pragma unroll
            for (int c = 0; c < 2; c++) {
                async16(smem + pb * 4096 +         (c * 64 + w * 16) * 32,
                        ga + (long)(c * 64 + w * 16) * E + kk2);
                async16(smem + pb * 4096 + 12288 + (c * 64 + w * 16) * 32,
                        gb + (long)(c * 64 + w * 16) * E + kk2);
            }
        }

        const __bf16* Asb = smem + cur * 4096;
        const __bf16* Bsb = smem + cur * 4096 + 12288;
        bf16x8 a[4], b[4];
        #pragma unroll
        for (int i = 0; i < 4; i++)
            a[i] = *reinterpret_cast<const bf16x8*>(
                &Asb[(wm * 64 + i * 16 + l16) * 32 + (quad ^ csw) * 8]);
        #pragma unroll
        for (int j = 0; j < 4; j++)
            b[j] = *reinterpret_cast<const bf16x8*>(
                &Bsb[(wn * 64 + j * 16 + l16) * 32 + (quad ^ csw) * 8]);
        #pragma unroll
        for (int i = 0; i < 4; i++)
            #pragma unroll
            for (int j = 0; j < 4; j++)
                acc[i][j] = __builtin_amdgcn_mfma_f32_16x16x32_bf16(a[i], b[j], acc[i][j], 0, 0, 0);

        cur = (cur == 2) ? 0 : cur + 1;
    }

    // ---- epilogues: proj-proven index math, direct stores ----
    const int region = nbase >> 10;           // block-uniform 0=K 1=V 2=Q
    const int bb = mbase >> 11;
    __bf16* vt = kvq + RSZ;                   // V^T region: [B,H,DK,S]
    __bf16* dst = kvq + (region == 2 ? 2 * RSZ : 0);
    float th[4];
    if (region == 2) {
        #pragma unroll
        for (int j = 0; j < 4; j++) th[j] = theta[j * 16 + l16];
    }
    #pragma unroll
    for (int i = 0; i < 4; i++) {
        const int row0 = mbase + wm * 64 + i * 16 + quad * 4;
        #pragma unroll
        for (int j = 0; j < 4; j++) {
            const int cir = (nbase & 1023) + wn * 64 + j * 16 + l16;
            const int h = cir >> 6, d = cir & 63;
            if (region == 1) {
                // V^T[b][h][d][s]: 4 consecutive s -> one 8B store
                bf16x4 pk;
                #pragma unroll
                for (int r = 0; r < 4; r++) pk[r] = (__bf16)acc[i][j][r];
                const int s0 = row0 & 2047;
                *reinterpret_cast<bf16x4*>(
                    &vt[((long)(bb * H + h) * DK + d) * S + s0]) = pk;
            } else {
                #pragma unroll
                for (int r = 0; r < 4; r++) {
                    const int s = (row0 + r) & 2047;
                    float v = acc[i][j][r];
                    if (region == 2) v = cosf(v + th[j]) * QSCALE;  // fold 1/sqrt(DK)*log2e
                    dst[((long)(bb * H + h) * S + s) * DK + d] = (__bf16)v;
                }
            }
        }
    }
}

// ---------------- attention v10 (verified 53.2us): S^T + KT=64 + distance-2 ----------------
// Best measured attn across v10-v14 (v11 ILP: neutral; v12 reg-direct K/V:
// 2.4x worse; v13 small-tile occupancy: 1.37x worse; v14 in-reg P: 1.06x
// worse). Kept verbatim.
__global__ __launch_bounds__(256, 2)
void attn_kernel(const __bf16* __restrict__ q_ws, const __bf16* __restrict__ k_ws,
                 const __bf16* __restrict__ v_ws, float* __restrict__ out) {
    __shared__ __align__(1024) __bf16 Ks[3][64 * 64];   // [key][d] swizzled, 8 KB each
    __shared__ __align__(1024) __bf16 Vs[3][64 * 64];   // [d][key] swizzled, 8 KB each
    __shared__ __align__(16)   __bf16 Pl[4][32 * 72];   // per-wave P [qrow][key], stride 72
    __shared__ __align__(16)   float  ls_lds[4][32];

    const int lane = threadIdx.x & 63;
    const int w    = threadIdx.x >> 6;          // 0..3
    const int quad = lane >> 4;
    const int l16  = lane & 15;

    // XCD swizzle: 4 bh per id%8 class -> per-XCD K/V set 2MB < 4MB L2 (R6-verified)
    const int id    = blockIdx.x;
    const int bh    = (id & 7) + 8 * ((id >> 3) & 3);
    const int qbase = (id >> 5) * 128 + w * 32;  // wave owns 32 q-rows

    const __bf16* qp = q_ws + (long)bh * S * DK;
    const __bf16* kp = k_ws + (long)bh * S * DK;
    const __bf16* vp = v_ws + (long)bh * DK * S;   // [DK][S]

    // staging: 8 rows x 8 chunks(16B) per async16; source chunk XOR-swizzled
    const int sr  = lane >> 3;
    const int scs = (lane & 7) ^ sr;

    // Q B-frags resident: B[k=d=ks*32+quad*8+j][n=qrow=nt*16+l16]
    bf16x8 bq[2][2];
    #pragma unroll
    for (int nt = 0; nt < 2; nt++)
        #pragma unroll
        for (int ks = 0; ks < 2; ks++)
            bq[nt][ks] = *reinterpret_cast<const bf16x8*>(
                qp + (long)(qbase + nt * 16 + l16) * DK + ks * 32 + quad * 8);

    f32x4 o[2][4];     // O[qrow-tile mt][d-tile nt]
    #pragma unroll
    for (int i = 0; i < 2; i++)
        #pragma unroll
        for (int j = 0; j < 4; j++) o[i][j] = f32x4{0.f, 0.f, 0.f, 0.f};
    float lsum[2] = {0.f, 0.f};   // per-lane partial row sums, qrow = nt*16+l16

    // prologue: tiles 0,1 into buffers 0,1 — 4 DMA issues per tile per wave
    #pragma unroll
    for (int pt = 0; pt < 2; pt++) {
        #pragma unroll
        for (int i = 0; i < 2; i++) {
            const int row = w * 16 + i * 8;
            async16(&Ks[pt][row * 64], kp + (long)(pt * 64 + row + sr) * DK + scs * 8);
            async16(&Vs[pt][row * 64], vp + (long)(row + sr) * S + pt * 64 + scs * 8);
        }
    }

    int cur = 0;
    constexpr int ITERS = S / 64;   // 32
    for (int it = 0; it < ITERS; it++) {
        if (it < ITERS - 1) asm volatile("s_waitcnt vmcnt(4)" ::: "memory");
        else                asm volatile("s_waitcnt vmcnt(0)" ::: "memory");
        asm volatile("s_barrier" ::: "memory");   // raw: no drain

        if (it + 2 < ITERS) {
            const int kt2 = (it + 2) * 64;
            const int pb  = (cur == 0) ? 2 : cur - 1;
            #pragma unroll
            for (int i = 0; i < 2; i++) {
                const int row = w * 16 + i * 8;
                async16(&Ks[pb][row * 64], kp + (long)(kt2 + row + sr) * DK + scs * 8);
                async16(&Vs[pb][row * 64], vp + (long)(row + sr) * S + kt2 + scs * 8);
            }
        }

        // ---- S^T = K Q^T : C[key(regs) 64][qrow(lanes) 32] ----
        f32x4 sacc[4][2];  // [key-tile mt][qrow-tile nt]
        #pragma unroll
        for (int i = 0; i < 4; i++)
            #pragma unroll
            for (int j = 0; j < 2; j++) sacc[i][j] = f32x4{0.f, 0.f, 0.f, 0.f};
        #pragma unroll
        for (int ks = 0; ks < 2; ks++) {
            bf16x8 ak[4];
            #pragma unroll
            for (int mt = 0; mt < 4; mt++)
                ak[mt] = *reinterpret_cast<const bf16x8*>(
                    &Ks[cur][(mt * 16 + l16) * 64 + ((ks * 4 + quad) ^ (l16 & 7)) * 8]);
            #pragma unroll
            for (int mt = 0; mt < 4; mt++)
                #pragma unroll
                for (int nt = 0; nt < 2; nt++)
                    sacc[mt][nt] = __builtin_amdgcn_mfma_f32_16x16x32_bf16(
                        ak[mt], bq[nt][ks], sacc[mt][nt], 0, 0, 0);
        }

        // ---- P = exp2(S^T): 4 consecutive keys (regs) -> one b64 store ----
        #pragma unroll
        for (int mt = 0; mt < 4; mt++)
            #pragma unroll
            for (int nt = 0; nt < 2; nt++) {
                float p0 = __builtin_amdgcn_exp2f(sacc[mt][nt][0]);
                float p1 = __builtin_amdgcn_exp2f(sacc[mt][nt][1]);
                float p2 = __builtin_amdgcn_exp2f(sacc[mt][nt][2]);
                float p3 = __builtin_amdgcn_exp2f(sacc[mt][nt][3]);
                lsum[nt] += (p0 + p1) + (p2 + p3);
                bf16x4 pk;
                pk[0] = (__bf16)p0; pk[1] = (__bf16)p1;
                pk[2] = (__bf16)p2; pk[3] = (__bf16)p3;
                *reinterpret_cast<bf16x4*>(
                    &Pl[w][(nt * 16 + l16) * 72 + mt * 16 + quad * 4]) = pk;
            }

        // ---- O += P V : A=P[m=qrow][k=key], B=V[k=key][n=d], 2 k-halves ----
        #pragma unroll
        for (int kh = 0; kh < 2; kh++) {
            bf16x8 bv[4];
            #pragma unroll
            for (int nt = 0; nt < 4; nt++)
                bv[nt] = *reinterpret_cast<const bf16x8*>(
                    &Vs[cur][(nt * 16 + l16) * 64 + ((kh * 4 + quad) ^ (l16 & 7)) * 8]);
            #pragma unroll
            for (int mt = 0; mt < 2; mt++) {
                bf16x8 ap = *reinterpret_cast<const bf16x8*>(
                    &Pl[w][(mt * 16 + l16) * 72 + kh * 32 + quad * 8]);
                #pragma unroll
                for (int nt = 0; nt < 4; nt++)
                    o[mt][nt] = __builtin_amdgcn_mfma_f32_16x16x32_bf16(
                        ap, bv[nt], o[mt][nt], 0, 0, 0);
            }
        }

        cur = (cur == 2) ? 0 : cur + 1;
    }

    // ---- finalize l: reduce partials across the 4 quads, broadcast via LDS ----
    #pragma unroll
    for (int nt = 0; nt < 2; nt++) {
        float v = lsum[nt];
        v += __shfl_xor(v, 16);
        v += __shfl_xor(v, 32);
        ls_lds[w][nt * 16 + l16] = v;   // quads duplicate-write same value (benign)
    }

    // ---- epilogue: out[b][s][h*64+d] = O / l ----
    const int b = bh >> 4, h = bh & 15;
    #pragma unroll
    for (int mt = 0; mt < 2; mt++) {
        f32x4 lv = *reinterpret_cast<const f32x4*>(&ls_lds[w][mt * 16 + quad * 4]);
        #pragma unroll
        for (int r = 0; r < 4; r++) {
            const float inv = 1.0f / lv[r];
            const int srow = qbase + mt * 16 + quad * 4 + r;
            #pragma unroll
            for (int nt = 0; nt < 4; nt++)
                out[(long)(b * S + srow) * E + h * DK + nt * 16 + l16] = o[mt][nt][r] * inv;
        }
    }
}

extern "C" void kernel_launch(void* const* d_in, const int* in_sizes, int n_in,
                              void* d_out, int out_size, void* d_ws, size_t ws_size,
                              hipStream_t stream) {
    const float* x     = (const float*)d_in[0];
    const float* Wk    = (const float*)d_in[1];
    const float* Wv    = (const float*)d_in[2];
    const float* Wq    = (const float*)d_in[3];
    const float* theta = (const float*)d_in[4];
    float* out = (float*)d_out;

    // ws: kvq[3*RSZ: K | V^T | Q] -- 25.2 MB (attn-proven available).
    // d_out (16.8 MB) doubles as scratch for xb (8.4 MB) + wall (6.3 MB)
    // during cvt+qkv; attn fully overwrites it afterwards.
    __bf16* kvq  = (__bf16*)d_ws;
    __bf16* k_ws = kvq;
    __bf16* v_t  = kvq + RSZ;
    __bf16* q_ws = kvq + 2 * RSZ;
    __bf16* xb   = (__bf16*)d_out;
    __bf16* wall = xb + (long)M * E;

    dim3 blk(256);
    cvt_kernel<<<dim3(7168), blk, 0, stream>>>(x, Wk, Wv, Wq, xb, wall);
    qkv_gemm<<<dim3(N3 / 128, M / 128), blk, 0, stream>>>(xb, wall, theta, kvq);
    attn_kernel<<<dim3(512), blk, 0, stream>>>(q_ws, k_ws, v_t, out);
}

// Round 9
// 172.930 us; speedup vs baseline: 1.0641x; 1.0040x over previous
//
#include <hip/hip_runtime.h>
#include <hip/hip_bf16.h>

// Problem constants
constexpr int B  = 2;
constexpr int S  = 2048;
constexpr int E  = 1024;
constexpr int H  = 16;
constexpr int DK = 64;
constexpr int M  = B * S;            // 4096 rows of x
constexpr int N3 = 3 * E;            // stacked [Wk; Wv; Wq]
constexpr long RSZ = (long)B * H * S * DK;  // one output region (4.19M elems)

// Q scale: 1/sqrt(DK) * log2(e) -> softmax via raw v_exp_f32 (base-2), no mul.
#define QSCALE 0.18033688011112042f

using bf16x8 = __attribute__((ext_vector_type(8))) __bf16;
using bf16x4 = __attribute__((ext_vector_type(4))) __bf16;
using f32x4  = __attribute__((ext_vector_type(4))) float;

// async global->LDS, 16B/lane; LDS base wave-uniform, lane i lands at +i*16 B.
__device__ __forceinline__ void async16(__bf16* lds, const __bf16* g) {
    __builtin_amdgcn_global_load_lds(
        (const __attribute__((address_space(1))) void*)g,
        (__attribute__((address_space(3))) void*)lds, 16, 0, 0);
}

// ---------------- cvt: x and stacked W's -> bf16 (into d_out scratch) ----------------
// ws_size < 39.8MB (R0-R6 evidence), so xb/wall live in d_out (16.8 MB,
// fully overwritten by attn at the very end): xb 8.4 + wall 6.3 = 14.7 MB.
__global__ __launch_bounds__(256)
void cvt_kernel(const float* __restrict__ x, const float* __restrict__ Wk,
                const float* __restrict__ Wv, const float* __restrict__ Wq,
                __bf16* __restrict__ xb, __bf16* __restrict__ wall) {
    const long e = ((long)blockIdx.x * 256 + threadIdx.x) * 4;
    const float* src;
    __bf16* dst;
    if (e < (long)M * E) { src = x + e; dst = xb + e; }
    else {
        const long e2 = e - (long)M * E;
        const int which = (int)(e2 >> 20);
        const long off  = e2 & ((1L << 20) - 1);
        src = (which == 0 ? Wk : which == 1 ? Wv : Wq) + off;
        dst = wall + e2;
    }
    float4 f = *reinterpret_cast<const float4*>(src);
    bf16x4 o;
    o[0] = (__bf16)f.x; o[1] = (__bf16)f.y; o[2] = (__bf16)f.z; o[3] = (__bf16)f.w;
    *reinterpret_cast<bf16x4*>(dst) = o;
}

// ---------------- QKV GEMM v6: v5 core + 2D XCD-locality block remap ----------------
// R8 accounting: qkv ~45-54us (hides just under attn in top-5) vs 17us LDS /
// 12us MFMA floors -> read-traffic-bound: 768 blocks x 1MB panels = 768 MB
// through cache; default round-robin dispatch gives each XCD a 14.7MB working
// set >> 4MB L2 -> L3-rate reads (~47us). Remap: xcd = id&7 (round-robin
// dispatch), each XCD owns a contiguous 12col x 8row region; within-XCD
// row-major order -> hot set = 12 B-panels (3MB) + 1 A-panel = 3.5MB < L2.
// Bijective: 768 = 8 x (12x8). Kernel math/sync/epilogues identical to R8.
__global__ __launch_bounds__(256, 3)
void qkv_gemm(const __bf16* __restrict__ xb, const __bf16* __restrict__ wall,
              const float* __restrict__ theta, __bf16* __restrict__ kvq) {
    __shared__ __align__(1024) __bf16 smem[6 * 128 * 32];   // A0|A1|A2|B0|B1|B2 = 48 KB

    const int t    = threadIdx.x;
    const int lane = t & 63;
    const int w    = t >> 6;
    const int quad = lane >> 4;
    const int l16  = lane & 15;
    const int wm   = w >> 1, wn = w & 1;      // 2x2 wave grid, 64x64 each

    // 2D XCD-locality remap (grid = 768 1-D blocks; 24 cols x 32 rows of 128)
    const int id   = blockIdx.x;
    const int xcd  = id & 7;
    const int lid  = id >> 3;                 // 0..95 within this XCD
    const int lr   = lid / 12, lc = lid % 12; // 8 rows x 12 cols per XCD
    const int mbase = ((xcd >> 1) * 8 + lr) * 128;   // row quarter per xcd pair
    const int nbase = ((xcd & 1) * 12 + lc) * 128;   // col half per xcd parity

    f32x4 acc[4][4];
    #pragma unroll
    for (int i = 0; i < 4; i++)
        #pragma unroll
        for (int j = 0; j < 4; j++)
            acc[i][j] = f32x4{0.f, 0.f, 0.f, 0.f};

    const int srow = lane >> 2;
    const int srcc = (lane & 3) ^ ((lane >> 3) & 3);
    const __bf16* ga = xb   + (long)(mbase + srow) * E + srcc * 8;
    const __bf16* gb = wall + (long)(nbase + srow) * E + srcc * 8;

    const int csw = (l16 >> 1) & 3;

    // prologue: tiles 0 and 1 into buffers 0 and 1 (8 loads outstanding)
    #pragma unroll
    for (int pt = 0; pt < 2; pt++) {
        #pragma unroll
        for (int c = 0; c < 2; c++) {
            async16(smem + pt * 4096 +         (c * 64 + w * 16) * 32,
                    ga + (long)(c * 64 + w * 16) * E + pt * 32);
            async16(smem + pt * 4096 + 12288 + (c * 64 + w * 16) * 32,
                    gb + (long)(c * 64 + w * 16) * E + pt * 32);
        }
    }

    int cur = 0;
    constexpr int ITERS = E / 32;   // 32
    for (int it = 0; it < ITERS; it++) {
        if (it < ITERS - 1) asm volatile("s_waitcnt vmcnt(4)" ::: "memory");
        else                asm volatile("s_waitcnt vmcnt(0)" ::: "memory");
        asm volatile("s_barrier" ::: "memory");   // raw: no drain

        if (it + 2 < ITERS) {
            const int pb  = (cur == 0) ? 2 : cur - 1;
            const int kk2 = (it + 2) * 32;
            #pragma unroll
            for (int c = 0; c < 2; c++) {
                async16(smem + pb * 4096 +         (c * 64 + w * 16) * 32,
                        ga + (long)(c * 64 + w * 16) * E + kk2);
                async16(smem + pb * 4096 + 12288 + (c * 64 + w * 16) * 32,
                        gb + (long)(c * 64 + w * 16) * E + kk2);
            }
        }

        const __bf16* Asb = smem + cur * 4096;
        const __bf16* Bsb = smem + cur * 4096 + 12288;
        bf16x8 a[4], b[4];
        #pragma unroll
        for (int i = 0; i < 4; i++)
            a[i] = *reinterpret_cast<const bf16x8*>(
                &Asb[(wm * 64 + i * 16 + l16) * 32 + (quad ^ csw) * 8]);
        #pragma unroll
        for (int j = 0; j < 4; j++)
            b[j] = *reinterpret_cast<const bf16x8*>(
                &Bsb[(wn * 64 + j * 16 + l16) * 32 + (quad ^ csw) * 8]);
        #pragma unroll
        for (int i = 0; i < 4; i++)
            #pragma unroll
            for (int j = 0; j < 4; j++)
                acc[i][j] = __builtin_amdgcn_mfma_f32_16x16x32_bf16(a[i], b[j], acc[i][j], 0, 0, 0);

        cur = (cur == 2) ? 0 : cur + 1;
    }

    // ---- epilogues: proj-proven index math, direct stores (R8-verified) ----
    const int region = nbase >> 10;           // block-uniform 0=K 1=V 2=Q
    const int bb = mbase >> 11;
    __bf16* vt = kvq + RSZ;                   // V^T region: [B,H,DK,S]
    __bf16* dst = kvq + (region == 2 ? 2 * RSZ : 0);
    float th[4];
    if (region == 2) {
        #pragma unroll
        for (int j = 0; j < 4; j++) th[j] = theta[j * 16 + l16];
    }
    #pragma unroll
    for (int i = 0; i < 4; i++) {
        const int row0 = mbase + wm * 64 + i * 16 + quad * 4;
        #pragma unroll
        for (int j = 0; j < 4; j++) {
            const int cir = (nbase & 1023) + wn * 64 + j * 16 + l16;
            const int h = cir >> 6, d = cir & 63;
            if (region == 1) {
                // V^T[b][h][d][s]: 4 consecutive s -> one 8B store
                bf16x4 pk;
                #pragma unroll
                for (int r = 0; r < 4; r++) pk[r] = (__bf16)acc[i][j][r];
                const int s0 = row0 & 2047;
                *reinterpret_cast<bf16x4*>(
                    &vt[((long)(bb * H + h) * DK + d) * S + s0]) = pk;
            } else {
                #pragma unroll
                for (int r = 0; r < 4; r++) {
                    const int s = (row0 + r) & 2047;
                    float v = acc[i][j][r];
                    if (region == 2) v = cosf(v + th[j]) * QSCALE;  // fold 1/sqrt(DK)*log2e
                    dst[((long)(bb * H + h) * S + s) * DK + d] = (__bf16)v;
                }
            }
        }
    }
}

// ---------------- attention v10 (verified 53-54.6us): S^T + KT=64 + distance-2 ----------------
// Best measured attn across v10-v14 (v11 ILP: neutral; v12 reg-direct K/V:
// 2.4x worse; v13 small-tile occupancy: 1.37x worse; v14 in-reg P: 1.06x
// worse). Kept verbatim.
__global__ __launch_bounds__(256, 2)
void attn_kernel(const __bf16* __restrict__ q_ws, const __bf16* __restrict__ k_ws,
                 const __bf16* __restrict__ v_ws, float* __restrict__ out) {
    __shared__ __align__(1024) __bf16 Ks[3][64 * 64];   // [key][d] swizzled, 8 KB each
    __shared__ __align__(1024) __bf16 Vs[3][64 * 64];   // [d][key] swizzled, 8 KB each
    __shared__ __align__(16)   __bf16 Pl[4][32 * 72];   // per-wave P [qrow][key], stride 72
    __shared__ __align__(16)   float  ls_lds[4][32];

    const int lane = threadIdx.x & 63;
    const int w    = threadIdx.x >> 6;          // 0..3
    const int quad = lane >> 4;
    const int l16  = lane & 15;

    // XCD swizzle: 4 bh per id%8 class -> per-XCD K/V set 2MB < 4MB L2 (R6-verified)
    const int id    = blockIdx.x;
    const int bh    = (id & 7) + 8 * ((id >> 3) & 3);
    const int qbase = (id >> 5) * 128 + w * 32;  // wave owns 32 q-rows

    const __bf16* qp = q_ws + (long)bh * S * DK;
    const __bf16* kp = k_ws + (long)bh * S * DK;
    const __bf16* vp = v_ws + (long)bh * DK * S;   // [DK][S]

    // staging: 8 rows x 8 chunks(16B) per async16; source chunk XOR-swizzled
    const int sr  = lane >> 3;
    const int scs = (lane & 7) ^ sr;

    // Q B-frags resident: B[k=d=ks*32+quad*8+j][n=qrow=nt*16+l16]
    bf16x8 bq[2][2];
    #pragma unroll
    for (int nt = 0; nt < 2; nt++)
        #pragma unroll
        for (int ks = 0; ks < 2; ks++)
            bq[nt][ks] = *reinterpret_cast<const bf16x8*>(
                qp + (long)(qbase + nt * 16 + l16) * DK + ks * 32 + quad * 8);

    f32x4 o[2][4];     // O[qrow-tile mt][d-tile nt]
    #pragma unroll
    for (int i = 0; i < 2; i++)
        #pragma unroll
        for (int j = 0; j < 4; j++) o[i][j] = f32x4{0.f, 0.f, 0.f, 0.f};
    float lsum[2] = {0.f, 0.f};   // per-lane partial row sums, qrow = nt*16+l16

    // prologue: tiles 0,1 into buffers 0,1 — 4 DMA issues per tile per wave
    #pragma unroll
    for (int pt = 0; pt < 2; pt++) {
        #pragma unroll
        for (int i = 0; i < 2; i++) {
            const int row = w * 16 + i * 8;
            async16(&Ks[pt][row * 64], kp + (long)(pt * 64 + row + sr) * DK + scs * 8);
            async16(&Vs[pt][row * 64], vp + (long)(row + sr) * S + pt * 64 + scs * 8);
        }
    }

    int cur = 0;
    constexpr int ITERS = S / 64;   // 32
    for (int it = 0; it < ITERS; it++) {
        if (it < ITERS - 1) asm volatile("s_waitcnt vmcnt(4)" ::: "memory");
        else                asm volatile("s_waitcnt vmcnt(0)" ::: "memory");
        asm volatile("s_barrier" ::: "memory");   // raw: no drain

        if (it + 2 < ITERS) {
            const int kt2 = (it + 2) * 64;
            const int pb  = (cur == 0) ? 2 : cur - 1;
            #pragma unroll
            for (int i = 0; i < 2; i++) {
                const int row = w * 16 + i * 8;
                async16(&Ks[pb][row * 64], kp + (long)(kt2 + row + sr) * DK + scs * 8);
                async16(&Vs[pb][row * 64], vp + (long)(row + sr) * S + kt2 + scs * 8);
            }
        }

        // ---- S^T = K Q^T : C[key(regs) 64][qrow(lanes) 32] ----
        f32x4 sacc[4][2];  // [key-tile mt][qrow-tile nt]
        #pragma unroll
        for (int i = 0; i < 4; i++)
            #pragma unroll
            for (int j = 0; j < 2; j++) sacc[i][j] = f32x4{0.f, 0.f, 0.f, 0.f};
        #pragma unroll
        for (int ks = 0; ks < 2; ks++) {
            bf16x8 ak[4];
            #pragma unroll
            for (int mt = 0; mt < 4; mt++)
                ak[mt] = *reinterpret_cast<const bf16x8*>(
                    &Ks[cur][(mt * 16 + l16) * 64 + ((ks * 4 + quad) ^ (l16 & 7)) * 8]);
            #pragma unroll
            for (int mt = 0; mt < 4; mt++)
                #pragma unroll
                for (int nt = 0; nt < 2; nt++)
                    sacc[mt][nt] = __builtin_amdgcn_mfma_f32_16x16x32_bf16(
                        ak[mt], bq[nt][ks], sacc[mt][nt], 0, 0, 0);
        }

        // ---- P = exp2(S^T): 4 consecutive keys (regs) -> one b64 store ----
        #pragma unroll
        for (int mt = 0; mt < 4; mt++)
            #pragma unroll
            for (int nt = 0; nt < 2; nt++) {
                float p0 = __builtin_amdgcn_exp2f(sacc[mt][nt][0]);
                float p1 = __builtin_amdgcn_exp2f(sacc[mt][nt][1]);
                float p2 = __builtin_amdgcn_exp2f(sacc[mt][nt][2]);
                float p3 = __builtin_amdgcn_exp2f(sacc[mt][nt][3]);
                lsum[nt] += (p0 + p1) + (p2 + p3);
                bf16x4 pk;
                pk[0] = (__bf16)p0; pk[1] = (__bf16)p1;
                pk[2] = (__bf16)p2; pk[3] = (__bf16)p3;
                *reinterpret_cast<bf16x4*>(
                    &Pl[w][(nt * 16 + l16) * 72 + mt * 16 + quad * 4]) = pk;
            }

        // ---- O += P V : A=P[m=qrow][k=key], B=V[k=key][n=d], 2 k-halves ----
        #pragma unroll
        for (int kh = 0; kh < 2; kh++) {
            bf16x8 bv[4];
            #pragma unroll
            for (int nt = 0; nt < 4; nt++)
                bv[nt] = *reinterpret_cast<const bf16x8*>(
                    &Vs[cur][(nt * 16 + l16) * 64 + ((kh * 4 + quad) ^ (l16 & 7)) * 8]);
            #pragma unroll
            for (int mt = 0; mt < 2; mt++) {
                bf16x8 ap = *reinterpret_cast<const bf16x8*>(
                    &Pl[w][(mt * 16 + l16) * 72 + kh * 32 + quad * 8]);
                #pragma unroll
                for (int nt = 0; nt < 4; nt++)
                    o[mt][nt] = __builtin_amdgcn_mfma_f32_16x16x32_bf16(
                        ap, bv[nt], o[mt][nt], 0, 0, 0);
            }
        }

        cur = (cur == 2) ? 0 : cur + 1;
    }

    // ---- finalize l: reduce partials across the 4 quads, broadcast via LDS ----
    #pragma unroll
    for (int nt = 0; nt < 2; nt++) {
        float v = lsum[nt];
        v += __shfl_xor(v, 16);
        v += __shfl_xor(v, 32);
        ls_lds[w][nt * 16 + l16] = v;   // quads duplicate-write same value (benign)
    }

    // ---- epilogue: out[b][s][h*64+d] = O / l ----
    const int b = bh >> 4, h = bh & 15;
    #pragma unroll
    for (int mt = 0; mt < 2; mt++) {
        f32x4 lv = *reinterpret_cast<const f32x4*>(&ls_lds[w][mt * 16 + quad * 4]);
        #pragma unroll
        for (int r = 0; r < 4; r++) {
            const float inv = 1.0f / lv[r];
            const int srow = qbase + mt * 16 + quad * 4 + r;
            #pragma unroll
            for (int nt = 0; nt < 4; nt++)
                out[(long)(b * S + srow) * E + h * DK + nt * 16 + l16] = o[mt][nt][r] * inv;
        }
    }
}

extern "C" void kernel_launch(void* const* d_in, const int* in_sizes, int n_in,
                              void* d_out, int out_size, void* d_ws, size_t ws_size,
                              hipStream_t stream) {
    const float* x     = (const float*)d_in[0];
    const float* Wk    = (const float*)d_in[1];
    const float* Wv    = (const float*)d_in[2];
    const float* Wq    = (const float*)d_in[3];
    const float* theta = (const float*)d_in[4];
    float* out = (float*)d_out;

    // ws: kvq[3*RSZ: K | V^T | Q] -- 25.2 MB (attn-proven available).
    // d_out (16.8 MB) doubles as scratch for xb (8.4 MB) + wall (6.3 MB)
    // during cvt+qkv; attn fully overwrites it afterwards.
    __bf16* kvq  = (__bf16*)d_ws;
    __bf16* k_ws = kvq;
    __bf16* v_t  = kvq + RSZ;
    __bf16* q_ws = kvq + 2 * RSZ;
    __bf16* xb   = (__bf16*)d_out;
    __bf16* wall = xb + (long)M * E;

    dim3 blk(256);
    cvt_kernel<<<dim3(7168), blk, 0, stream>>>(x, Wk, Wv, Wq, xb, wall);
    qkv_gemm<<<dim3(768), blk, 0, stream>>>(xb, wall, theta, kvq);
    attn_kernel<<<dim3(512), blk, 0, stream>>>(q_ws, k_ws, v_t, out);
}

// Round 10
// 167.686 us; speedup vs baseline: 1.0974x; 1.0313x over previous
//
#include <hip/hip_runtime.h>
#include <hip/hip_bf16.h>

// Problem constants
constexpr int B  = 2;
constexpr int S  = 2048;
constexpr int E  = 1024;
constexpr int H  = 16;
constexpr int DK = 64;
constexpr int M  = B * S;            // 4096 rows of x
constexpr int N3 = 3 * E;            // stacked [Wk; Wv; Wq]
constexpr long RSZ = (long)B * H * S * DK;  // one output region (4.19M elems)

// Q scale: 1/sqrt(DK) * log2(e) -> softmax via raw v_exp_f32 (base-2), no mul.
#define QSCALE 0.18033688011112042f

using bf16x8 = __attribute__((ext_vector_type(8))) __bf16;
using bf16x4 = __attribute__((ext_vector_type(4))) __bf16;
using f32x4  = __attribute__((ext_vector_type(4))) float;

// async global->LDS, 16B/lane; LDS base wave-uniform, lane i lands at +i*16 B.
__device__ __forceinline__ void async16(__bf16* lds, const __bf16* g) {
    __builtin_amdgcn_global_load_lds(
        (const __attribute__((address_space(1))) void*)g,
        (__attribute__((address_space(3))) void*)lds, 16, 0, 0);
}

// ---------------- cvt: x and stacked W's -> bf16 (into d_out scratch) ----------------
__global__ __launch_bounds__(256)
void cvt_kernel(const float* __restrict__ x, const float* __restrict__ Wk,
                const float* __restrict__ Wv, const float* __restrict__ Wq,
                __bf16* __restrict__ xb, __bf16* __restrict__ wall) {
    const long e = ((long)blockIdx.x * 256 + threadIdx.x) * 4;
    const float* src;
    __bf16* dst;
    if (e < (long)M * E) { src = x + e; dst = xb + e; }
    else {
        const long e2 = e - (long)M * E;
        const int which = (int)(e2 >> 20);
        const long off  = e2 & ((1L << 20) - 1);
        src = (which == 0 ? Wk : which == 1 ? Wv : Wq) + off;
        dst = wall + e2;
    }
    float4 f = *reinterpret_cast<const float4*>(src);
    bf16x4 o;
    o[0] = (__bf16)f.x; o[1] = (__bf16)f.y; o[2] = (__bf16)f.z; o[3] = (__bf16)f.w;
    *reinterpret_cast<bf16x4*>(dst) = o;
}

// ---------------- QKV GEMM v7: coalesced K/Q epilogue via LDS bounce ----------------
// R9 post-mortem: XCD remap neutral -> qkv is NOT read-traffic-bound. Measured
// anchors (R6: overhead=32us) give qkv ~70-78us vs ~28us K-loop roofline. The
// K/Q epilogues issued 64 scalar 2B stores/thread (4x32B scattered segments
// per inst, 8.4M insts, ~55us of TA store-issue) -- also explains R6's
// all-idle counter signature. v7: bounce acc through an LDS tile [s][d]
// (stride 132 -> conflict-free quad spread on ds_write_b16), read back bf16x8
// row-chunks, store 8x16B coalesced insts/thread (8x128B segments per inst).
// V path keeps its verified transposed-tile bounce. K-loop/staging unchanged.
__global__ __launch_bounds__(256, 3)
void qkv_gemm(const __bf16* __restrict__ xb, const __bf16* __restrict__ wall,
              const float* __restrict__ theta, __bf16* __restrict__ kvq) {
    __shared__ __align__(1024) __bf16 smem[6 * 128 * 32];   // A0|A1|A2|B0|B1|B2 = 48 KB
    __bf16* tile = smem;   // epilogue alias: V: 128x128; K/Q: 128x132 = 33 KB

    const int t    = threadIdx.x;
    const int lane = t & 63;
    const int w    = t >> 6;
    const int quad = lane >> 4;
    const int l16  = lane & 15;
    const int wm   = w >> 1, wn = w & 1;      // 2x2 wave grid, 64x64 each

    // 2D XCD-locality remap (neutral in R9 but harmless; grid = 768 blocks)
    const int id   = blockIdx.x;
    const int xcd  = id & 7;
    const int lid  = id >> 3;                 // 0..95 within this XCD
    const int lr   = lid / 12, lc0 = lid % 12;
    const int mbase = ((xcd >> 1) * 8 + lr) * 128;
    const int nbase = ((xcd & 1) * 12 + lc0) * 128;

    f32x4 acc[4][4];
    #pragma unroll
    for (int i = 0; i < 4; i++)
        #pragma unroll
        for (int j = 0; j < 4; j++)
            acc[i][j] = f32x4{0.f, 0.f, 0.f, 0.f};

    const int srow = lane >> 2;
    const int srcc = (lane & 3) ^ ((lane >> 3) & 3);
    const __bf16* ga = xb   + (long)(mbase + srow) * E + srcc * 8;
    const __bf16* gb = wall + (long)(nbase + srow) * E + srcc * 8;

    const int csw = (l16 >> 1) & 3;

    // prologue: tiles 0 and 1 into buffers 0 and 1 (8 loads outstanding)
    #pragma unroll
    for (int pt = 0; pt < 2; pt++) {
        #pragma unroll
        for (int c = 0; c < 2; c++) {
            async16(smem + pt * 4096 +         (c * 64 + w * 16) * 32,
                    ga + (long)(c * 64 + w * 16) * E + pt * 32);
            async16(smem + pt * 4096 + 12288 + (c * 64 + w * 16) * 32,
                    gb + (long)(c * 64 + w * 16) * E + pt * 32);
        }
    }

    int cur = 0;
    constexpr int ITERS = E / 32;   // 32
    for (int it = 0; it < ITERS; it++) {
        if (it < ITERS - 1) asm volatile("s_waitcnt vmcnt(4)" ::: "memory");
        else                asm volatile("s_waitcnt vmcnt(0)" ::: "memory");
        asm volatile("s_barrier" ::: "memory");   // raw: no drain

        if (it + 2 < ITERS) {
            const int pb  = (cur == 0) ? 2 : cur - 1;
            const int kk2 = (it + 2) * 32;
            #pragma unroll
            for (int c = 0; c < 2; c++) {
                async16(smem + pb * 4096 +         (c * 64 + w * 16) * 32,
                        ga + (long)(c * 64 + w * 16) * E + kk2);
                async16(smem + pb * 4096 + 12288 + (c * 64 + w * 16) * 32,
                        gb + (long)(c * 64 + w * 16) * E + kk2);
            }
        }

        const __bf16* Asb = smem + cur * 4096;
        const __bf16* Bsb = smem + cur * 4096 + 12288;
        bf16x8 a[4], b[4];
        #pragma unroll
        for (int i = 0; i < 4; i++)
            a[i] = *reinterpret_cast<const bf16x8*>(
                &Asb[(wm * 64 + i * 16 + l16) * 32 + (quad ^ csw) * 8]);
        #pragma unroll
        for (int j = 0; j < 4; j++)
            b[j] = *reinterpret_cast<const bf16x8*>(
                &Bsb[(wn * 64 + j * 16 + l16) * 32 + (quad ^ csw) * 8]);
        #pragma unroll
        for (int i = 0; i < 4; i++)
            #pragma unroll
            for (int j = 0; j < 4; j++)
                acc[i][j] = __builtin_amdgcn_mfma_f32_16x16x32_bf16(a[i], b[j], acc[i][j], 0, 0, 0);

        cur = (cur == 2) ? 0 : cur + 1;
    }

    const int region = nbase >> 10;           // block-uniform 0=K 1=V 2=Q
    const int bb = mbase >> 11;
    __syncthreads();                          // drain staging reads before aliasing smem
    if (region == 1) {
        // ---- V: transposed tile -> V^T [B,H,DK,S] (verified path, unchanged) ----
        #pragma unroll
        for (int i = 0; i < 4; i++) {
            const int cchunk = wm * 8 + i * 2 + (quad >> 1);
            #pragma unroll
            for (int j = 0; j < 4; j++) {
                const int cirb = wn * 64 + j * 16 + l16;
                const int cs = cchunk ^ l16;
                bf16x4 pk;
                #pragma unroll
                for (int r = 0; r < 4; r++) pk[r] = (__bf16)acc[i][j][r];
                *reinterpret_cast<bf16x4*>(&tile[cirb * 128 + cs * 8 + (quad & 1) * 4]) = pk;
            }
        }
        __syncthreads();
        const int h0 = (nbase & 1023) >> 6;
        __bf16* vt = kvq + RSZ;               // V^T region: [B,H,DK,S]
        #pragma unroll
        for (int p = 0; p < 8; p++) {
            const int dcol = p * 16 + (t >> 4);
            const int lc = t & 15;
            const int cs2 = lc ^ (dcol & 15);
            bf16x8 vv = *reinterpret_cast<const bf16x8*>(&tile[dcol * 128 + cs2 * 8]);
            const int hh = h0 + (dcol >> 6), d = dcol & 63;
            *reinterpret_cast<bf16x8*>(
                &vt[((long)(bb * H + hh) * DK + d) * S + (mbase & 2047) + lc * 8]) = vv;
        }
    } else {
        // ---- K/Q: [s][d] tile (stride 132) -> coalesced 16B stores ----
        __bf16* dst = kvq + (region == 2 ? 2 * RSZ : 0);
        float th[4];
        if (region == 2) {
            #pragma unroll
            for (int j = 0; j < 4; j++) th[j] = theta[j * 16 + l16];
        }
        #pragma unroll
        for (int i = 0; i < 4; i++) {
            #pragma unroll
            for (int j = 0; j < 4; j++) {
                const int c = wn * 64 + j * 16 + l16;
                #pragma unroll
                for (int r = 0; r < 4; r++) {
                    const int cir = wm * 64 + i * 16 + quad * 4 + r;
                    float v = acc[i][j][r];
                    if (region == 2) v = cosf(v + th[j]) * QSCALE;  // fold 1/sqrt(DK)*log2e
                    tile[cir * 132 + c] = (__bf16)v;
                }
            }
        }
        __syncthreads();
        const int h0 = (nbase & 1023) >> 6;
        #pragma unroll
        for (int p = 0; p < 8; p++) {
            const int row = p * 16 + (t >> 4);   // 0..127 (within-block s)
            const int lc  = t & 15;              // 8-elem chunk along d
            bf16x8 vv = *reinterpret_cast<const bf16x8*>(&tile[row * 132 + lc * 8]);
            const int s = (mbase + row) & 2047;
            const int h = h0 + (lc >> 3), d = (lc & 7) * 8;
            *reinterpret_cast<bf16x8*>(
                &dst[((long)(bb * H + h) * S + s) * DK + d]) = vv;
        }
    }
}

// ---------------- attention v10 (verified 53-54.6us): S^T + KT=64 + distance-2 ----------------
// Best measured attn across v10-v14 (v11 ILP: neutral; v12 reg-direct K/V:
// 2.4x worse; v13 small-tile occupancy: 1.37x worse; v14 in-reg P: 1.06x
// worse). Kept verbatim.
__global__ __launch_bounds__(256, 2)
void attn_kernel(const __bf16* __restrict__ q_ws, const __bf16* __restrict__ k_ws,
                 const __bf16* __restrict__ v_ws, float* __restrict__ out) {
    __shared__ __align__(1024) __bf16 Ks[3][64 * 64];   // [key][d] swizzled, 8 KB each
    __shared__ __align__(1024) __bf16 Vs[3][64 * 64];   // [d][key] swizzled, 8 KB each
    __shared__ __align__(16)   __bf16 Pl[4][32 * 72];   // per-wave P [qrow][key], stride 72
    __shared__ __align__(16)   float  ls_lds[4][32];

    const int lane = threadIdx.x & 63;
    const int w    = threadIdx.x >> 6;          // 0..3
    const int quad = lane >> 4;
    const int l16  = lane & 15;

    // XCD swizzle: 4 bh per id%8 class -> per-XCD K/V set 2MB < 4MB L2 (R6-verified)
    const int id    = blockIdx.x;
    const int bh    = (id & 7) + 8 * ((id >> 3) & 3);
    const int qbase = (id >> 5) * 128 + w * 32;  // wave owns 32 q-rows

    const __bf16* qp = q_ws + (long)bh * S * DK;
    const __bf16* kp = k_ws + (long)bh * S * DK;
    const __bf16* vp = v_ws + (long)bh * DK * S;   // [DK][S]

    // staging: 8 rows x 8 chunks(16B) per async16; source chunk XOR-swizzled
    const int sr  = lane >> 3;
    const int scs = (lane & 7) ^ sr;

    // Q B-frags resident: B[k=d=ks*32+quad*8+j][n=qrow=nt*16+l16]
    bf16x8 bq[2][2];
    #pragma unroll
    for (int nt = 0; nt < 2; nt++)
        #pragma unroll
        for (int ks = 0; ks < 2; ks++)
            bq[nt][ks] = *reinterpret_cast<const bf16x8*>(
                qp + (long)(qbase + nt * 16 + l16) * DK + ks * 32 + quad * 8);

    f32x4 o[2][4];     // O[qrow-tile mt][d-tile nt]
    #pragma unroll
    for (int i = 0; i < 2; i++)
        #pragma unroll
        for (int j = 0; j < 4; j++) o[i][j] = f32x4{0.f, 0.f, 0.f, 0.f};
    float lsum[2] = {0.f, 0.f};   // per-lane partial row sums, qrow = nt*16+l16

    // prologue: tiles 0,1 into buffers 0,1 — 4 DMA issues per tile per wave
    #pragma unroll
    for (int pt = 0; pt < 2; pt++) {
        #pragma unroll
        for (int i = 0; i < 2; i++) {
            const int row = w * 16 + i * 8;
            async16(&Ks[pt][row * 64], kp + (long)(pt * 64 + row + sr) * DK + scs * 8);
            async16(&Vs[pt][row * 64], vp + (long)(row + sr) * S + pt * 64 + scs * 8);
        }
    }

    int cur = 0;
    constexpr int ITERS = S / 64;   // 32
    for (int it = 0; it < ITERS; it++) {
        if (it < ITERS - 1) asm volatile("s_waitcnt vmcnt(4)" ::: "memory");
        else                asm volatile("s_waitcnt vmcnt(0)" ::: "memory");
        asm volatile("s_barrier" ::: "memory");   // raw: no drain

        if (it + 2 < ITERS) {
            const int kt2 = (it + 2) * 64;
            const int pb  = (cur == 0) ? 2 : cur - 1;
            #pragma unroll
            for (int i = 0; i < 2; i++) {
                const int row = w * 16 + i * 8;
                async16(&Ks[pb][row * 64], kp + (long)(kt2 + row + sr) * DK + scs * 8);
                async16(&Vs[pb][row * 64], vp + (long)(row + sr) * S + kt2 + scs * 8);
            }
        }

        // ---- S^T = K Q^T : C[key(regs) 64][qrow(lanes) 32] ----
        f32x4 sacc[4][2];  // [key-tile mt][qrow-tile nt]
        #pragma unroll
        for (int i = 0; i < 4; i++)
            #pragma unroll
            for (int j = 0; j < 2; j++) sacc[i][j] = f32x4{0.f, 0.f, 0.f, 0.f};
        #pragma unroll
        for (int ks = 0; ks < 2; ks++) {
            bf16x8 ak[4];
            #pragma unroll
            for (int mt = 0; mt < 4; mt++)
                ak[mt] = *reinterpret_cast<const bf16x8*>(
                    &Ks[cur][(mt * 16 + l16) * 64 + ((ks * 4 + quad) ^ (l16 & 7)) * 8]);
            #pragma unroll
            for (int mt = 0; mt < 4; mt++)
                #pragma unroll
                for (int nt = 0; nt < 2; nt++)
                    sacc[mt][nt] = __builtin_amdgcn_mfma_f32_16x16x32_bf16(
                        ak[mt], bq[nt][ks], sacc[mt][nt], 0, 0, 0);
        }

        // ---- P = exp2(S^T): 4 consecutive keys (regs) -> one b64 store ----
        #pragma unroll
        for (int mt = 0; mt < 4; mt++)
            #pragma unroll
            for (int nt = 0; nt < 2; nt++) {
                float p0 = __builtin_amdgcn_exp2f(sacc[mt][nt][0]);
                float p1 = __builtin_amdgcn_exp2f(sacc[mt][nt][1]);
                float p2 = __builtin_amdgcn_exp2f(sacc[mt][nt][2]);
                float p3 = __builtin_amdgcn_exp2f(sacc[mt][nt][3]);
                lsum[nt] += (p0 + p1) + (p2 + p3);
                bf16x4 pk;
                pk[0] = (__bf16)p0; pk[1] = (__bf16)p1;
                pk[2] = (__bf16)p2; pk[3] = (__bf16)p3;
                *reinterpret_cast<bf16x4*>(
                    &Pl[w][(nt * 16 + l16) * 72 + mt * 16 + quad * 4]) = pk;
            }

        // ---- O += P V : A=P[m=qrow][k=key], B=V[k=key][n=d], 2 k-halves ----
        #pragma unroll
        for (int kh = 0; kh < 2; kh++) {
            bf16x8 bv[4];
            #pragma unroll
            for (int nt = 0; nt < 4; nt++)
                bv[nt] = *reinterpret_cast<const bf16x8*>(
                    &Vs[cur][(nt * 16 + l16) * 64 + ((kh * 4 + quad) ^ (l16 & 7)) * 8]);
            #pragma unroll
            for (int mt = 0; mt < 2; mt++) {
                bf16x8 ap = *reinterpret_cast<const bf16x8*>(
                    &Pl[w][(mt * 16 + l16) * 72 + kh * 32 + quad * 8]);
                #pragma unroll
                for (int nt = 0; nt < 4; nt++)
                    o[mt][nt] = __builtin_amdgcn_mfma_f32_16x16x32_bf16(
                        ap, bv[nt], o[mt][nt], 0, 0, 0);
            }
        }

        cur = (cur == 2) ? 0 : cur + 1;
    }

    // ---- finalize l: reduce partials across the 4 quads, broadcast via LDS ----
    #pragma unroll
    for (int nt = 0; nt < 2; nt++) {
        float v = lsum[nt];
        v += __shfl_xor(v, 16);
        v += __shfl_xor(v, 32);
        ls_lds[w][nt * 16 + l16] = v;   // quads duplicate-write same value (benign)
    }

    // ---- epilogue: out[b][s][h*64+d] = O / l ----
    const int b = bh >> 4, h = bh & 15;
    #pragma unroll
    for (int mt = 0; mt < 2; mt++) {
        f32x4 lv = *reinterpret_cast<const f32x4*>(&ls_lds[w][mt * 16 + quad * 4]);
        #pragma unroll
        for (int r = 0; r < 4; r++) {
            const float inv = 1.0f / lv[r];
            const int srow = qbase + mt * 16 + quad * 4 + r;
            #pragma unroll
            for (int nt = 0; nt < 4; nt++)
                out[(long)(b * S + srow) * E + h * DK + nt * 16 + l16] = o[mt][nt][r] * inv;
        }
    }
}

extern "C" void kernel_launch(void* const* d_in, const int* in_sizes, int n_in,
                              void* d_out, int out_size, void* d_ws, size_t ws_size,
                              hipStream_t stream) {
    const float* x     = (const float*)d_in[0];
    const float* Wk    = (const float*)d_in[1];
    const float* Wv    = (const float*)d_in[2];
    const float* Wq    = (const float*)d_in[3];
    const float* theta = (const float*)d_in[4];
    float* out = (float*)d_out;

    // ws: kvq[3*RSZ: K | V^T | Q] -- 25.2 MB. d_out doubles as scratch for
    // xb (8.4 MB) + wall (6.3 MB) during cvt+qkv; attn fully overwrites it.
    __bf16* kvq  = (__bf16*)d_ws;
    __bf16* k_ws = kvq;
    __bf16* v_t  = kvq + RSZ;
    __bf16* q_ws = kvq + 2 * RSZ;
    __bf16* xb   = (__bf16*)d_out;
    __bf16* wall = xb + (long)M * E;

    dim3 blk(256);
    cvt_kernel<<<dim3(7168), blk, 0, stream>>>(x, Wk, Wv, Wq, xb, wall);
    qkv_gemm<<<dim3(768), blk, 0, stream>>>(xb, wall, theta, kvq);
    attn_kernel<<<dim3(512), blk, 0, stream>>>(q_ws, k_ws, v_t, out);
}